// Round 13
// baseline (65.704 us; speedup 1.0000x reference)
//
#include <hip/hip_runtime.h>

// out[t, j] = W[j, x[t]] + b[j]
//   x : [16384] int32, W : [1024, 50257] f32 row-major, b : [1024] f32
//   out: [16384, 1024] f32
//
// R12 (64.8us, WIN): lanes = 64 SORTED tokens, j wave-uniform per load
// instr -> wave coalescer merges same-line lanes: ~3.2M W transactions =
// the compulsory minimum (each (line,j) fetched once grid-wide).
// R13: harvest overheads. (1) software-pipeline: issue chunk-1's 16
// loads BEFORE the first barrier so their latency hides under chunk-0's
// store phase (3 barriers instead of 4, single 16.9KB tile -> still 8
// blocks/CU). (2) hipMemsetAsync replaces the zero_counts dispatch.

#define VOCAB 50257
#define DIM   1024
#define NBUCK ((VOCAB + 15) >> 4)     // 3142 line-groups
#define NXCD  8
#define TPB   64                      // tokens per block
#define JSL   128                     // j-slice per block
#define NJS   (DIM / JSL)             // 8 j-slices
#define TSTR  65                      // LDS tile stride (floats)

// ---------- sort pipeline (counting sort by v>>4) ----------

__global__ void hist_kernel(const int* __restrict__ x, int n, int* __restrict__ counts) {
    int i = blockIdx.x * blockDim.x + threadIdx.x;
    if (i < n) atomicAdd(&counts[x[i] >> 4], 1);
}

__global__ __launch_bounds__(256) void scan_kernel(const int* __restrict__ counts,
                                                   int* __restrict__ offs) {
    const int CHUNK = (NBUCK + 255) / 256;   // 13
    __shared__ int lds[256];
    const int tid = threadIdx.x;
    const int base = tid * CHUNK;
    int local[CHUNK];
    int s = 0;
#pragma unroll
    for (int k = 0; k < CHUNK; ++k) {
        int idx = base + k;
        int c = (idx < NBUCK) ? counts[idx] : 0;
        local[k] = s;
        s += c;
    }
    lds[tid] = s;
    __syncthreads();
    if (tid == 0) {
        int run = 0;
        for (int i = 0; i < 256; ++i) { int c = lds[i]; lds[i] = run; run += c; }
    }
    __syncthreads();
    const int boff = lds[tid];
#pragma unroll
    for (int k = 0; k < CHUNK; ++k) {
        int idx = base + k;
        if (idx < NBUCK) offs[idx] = boff + local[k];
    }
}

// Packs (v << 16) | t. Intra-bucket order nondeterministic but out[t]
// depends only on t's own v -> deterministic OUTPUT.
__global__ void scatter_kernel(const int* __restrict__ x, int n,
                               int* __restrict__ offs, int* __restrict__ order) {
    int i = blockIdx.x * blockDim.x + threadIdx.x;
    if (i < n) {
        int v = x[i];
        int pos = atomicAdd(&offs[v >> 4], 1);
        order[pos] = (v << 16) | i;
    }
}

// ---------- gather: lanes = sorted tokens, j uniform; pipelined ----------
__global__ __launch_bounds__(256) void lane_sorted_gather(
    const float* __restrict__ W,
    const float* __restrict__ bias,
    const int* __restrict__ order,
    float* __restrict__ out,
    int n, int q, int r)   // q = nblk/8, r = nblk%8 (bijective XCD chunking)
{
    extern __shared__ float lds[];
    float* tile = lds;                       // [64][TSTR]
    int* tTok = (int*)(lds + TPB * TSTR);    // [64]

    const int bid = blockIdx.x;
    const int xcd = bid & (NXCD - 1);
    const int idx = bid >> 3;
    const int chunk_base = (xcd < r) ? xcd * (q + 1) : r * (q + 1) + (xcd - r) * q;
    const int L = chunk_base + idx;          // logical: consecutive L on one XCD
    const int g  = L >> 3;                   // token group (groups contiguous/XCD)
    const int js = L & 7;                    // j-slice 0..7

    const int tid = threadIdx.x;
    const int wave = tid >> 6;
    const int lane = tid & 63;

    const int t0 = g * TPB;
    const int cnt = min(TPB, n - t0);

    const unsigned pk = (unsigned)order[t0 + (lane < cnt ? lane : 0)]; // coalesced
    const int vl = (int)(pk >> 16);          // this lane's token's v (sorted)
    if (wave == 0) tTok[lane] = (int)(pk & 0xFFFFu);

    const int jb0 = js * JSL;
    const float* __restrict__ Wv = W + vl;   // per-lane column base
    const int jw = jb0 + wave * 16;          // this wave's 16 js, chunk 0
    const int tok = tid >> 2;                // store phase: token 0..63
    const int qq = tid & 3;                  // quad within 64-float chunk

    // ---- chunk 0 loads (16/lane), ~13 segments/instr (sorted lanes) ----
    float a0[8], b0[8];
#pragma unroll
    for (int i = 0; i < 8; ++i) a0[i] = Wv[(size_t)(jw + i) * VOCAB];
#pragma unroll
    for (int i = 0; i < 8; ++i) b0[i] = Wv[(size_t)(jw + 8 + i) * VOCAB];
    __builtin_amdgcn_sched_barrier(0);
#pragma unroll
    for (int i = 0; i < 8; ++i) tile[lane * TSTR + wave * 16 + i] = a0[i];
#pragma unroll
    for (int i = 0; i < 8; ++i) tile[lane * TSTR + wave * 16 + 8 + i] = b0[i];

    // ---- chunk 1 loads issued NOW: latency hides under chunk-0 stores ----
    float a1[8], b1[8];
#pragma unroll
    for (int i = 0; i < 8; ++i) a1[i] = Wv[(size_t)(jw + 64 + i) * VOCAB];
#pragma unroll
    for (int i = 0; i < 8; ++i) b1[i] = Wv[(size_t)(jw + 72 + i) * VOCAB];
    __builtin_amdgcn_sched_barrier(0);

    __syncthreads();                         // tile(ch0) + tTok ready

    // ---- stores chunk 0: 4 threads/token, 64B contiguous per instr ----
    const int t_out = (tok < cnt) ? tTok[tok] : -1;
    if (t_out >= 0) {
        float* __restrict__ dst = out + (size_t)t_out * DIM + jb0;
#pragma unroll
        for (int k = 0; k < 4; ++k) {
            const int jloc = k * 16 + qq * 4;
            float4 w4 = *reinterpret_cast<const float4*>(&tile[tok * TSTR + jloc]);
            const float4 b4 = *reinterpret_cast<const float4*>(&bias[jb0 + jloc]);
            w4.x += b4.x; w4.y += b4.y; w4.z += b4.z; w4.w += b4.w;
            *reinterpret_cast<float4*>(dst + jloc) = w4;
        }
    }
    __syncthreads();                         // ch0 stores done reading tile

    // ---- write chunk 1 into tile (waitcnt on a1/b1 auto-inserted) ----
#pragma unroll
    for (int i = 0; i < 8; ++i) tile[lane * TSTR + wave * 16 + i] = a1[i];
#pragma unroll
    for (int i = 0; i < 8; ++i) tile[lane * TSTR + wave * 16 + 8 + i] = b1[i];
    __syncthreads();                         // tile(ch1) ready

    // ---- stores chunk 1 ----
    if (t_out >= 0) {
        float* __restrict__ dst = out + (size_t)t_out * DIM + jb0 + 64;
#pragma unroll
        for (int k = 0; k < 4; ++k) {
            const int jloc = k * 16 + qq * 4;
            float4 w4 = *reinterpret_cast<const float4*>(&tile[tok * TSTR + jloc]);
            const float4 b4 = *reinterpret_cast<const float4*>(&bias[jb0 + 64 + jloc]);
            w4.x += b4.x; w4.y += b4.y; w4.z += b4.z; w4.w += b4.w;
            *reinterpret_cast<float4*>(dst + jloc) = w4;
        }
    }
}

// fallback (round-1 kernel) if workspace too small / n too large for packing
__global__ __launch_bounds__(256) void gather_direct_kernel(
    const int* __restrict__ x,
    const float* __restrict__ W,
    const float* __restrict__ bias,
    float* __restrict__ out)
{
    const int t = blockIdx.x;
    const int v = x[t];
    const int j0 = threadIdx.x * 4;
    float4 rr;
    rr.x = W[(size_t)(j0 + 0) * VOCAB + v];
    rr.y = W[(size_t)(j0 + 1) * VOCAB + v];
    rr.z = W[(size_t)(j0 + 2) * VOCAB + v];
    rr.w = W[(size_t)(j0 + 3) * VOCAB + v];
    const float4 bb = *reinterpret_cast<const float4*>(bias + j0);
    rr.x += bb.x; rr.y += bb.y; rr.z += bb.z; rr.w += bb.w;
    *reinterpret_cast<float4*>(out + (size_t)t * DIM + j0) = rr;
}

extern "C" void kernel_launch(void* const* d_in, const int* in_sizes, int n_in,
                              void* d_out, int out_size, void* d_ws, size_t ws_size,
                              hipStream_t stream) {
    const int*   x    = (const int*)d_in[0];
    const float* W    = (const float*)d_in[1];
    const float* bias = (const float*)d_in[2];
    float*       out  = (float*)d_out;

    const int n = in_sizes[0];           // 16384 tokens

    const size_t need = (size_t)(2 * NBUCK + n) * sizeof(int);
    if (ws_size < need || n > 65536) {   // packing uses 16 bits for token id
        gather_direct_kernel<<<n, 256, 0, stream>>>(x, W, bias, out);
        return;
    }

    int* counts = (int*)d_ws;            // [NBUCK]
    int* offs   = counts + NBUCK;        // [NBUCK]
    int* order  = offs + NBUCK;          // [n] packed (v<<16 | t)

    const int tb = 256;
    hipMemsetAsync(counts, 0, NBUCK * sizeof(int), stream);   // graph-capturable
    hist_kernel<<<(n + tb - 1) / tb, tb, 0, stream>>>(x, n, counts);
    scan_kernel<<<1, tb, 0, stream>>>(counts, offs);
    scatter_kernel<<<(n + tb - 1) / tb, tb, 0, stream>>>(x, n, offs, order);

    const int ngroups = (n + TPB - 1) / TPB;     // 256
    const int nblk = ngroups * NJS;              // 2048
    const int q = nblk / NXCD, r = nblk % NXCD;
    const size_t lds_bytes = (TPB * TSTR) * sizeof(float) + TPB * sizeof(int);
    lane_sorted_gather<<<nblk, 256, lds_bytes, stream>>>(W, bias, order, out, n, q, r);
}

// Round 14
// 60.005 us; speedup vs baseline: 1.0950x; 1.0950x over previous
//
#include <hip/hip_runtime.h>

// out[t, j] = W[j, x[t]] + b[j]
//   x : [16384] int32, W : [1024, 50257] f32 row-major, b : [1024] f32
//   out: [16384, 1024] f32
//
// R12 (64.8us WIN): lanes = 64 SORTED tokens, j wave-uniform -> wave
// coalescer merges same-line lanes; ~3.2M W transactions = compulsory.
// R13 (neutral): chunk-1 pre-issue gained 0 -> gather latency already
// hidden by TLP; it sits at the TA-segment/HBM floor (~30-40us).
// R14: cut sort-pipeline overhead. Fuse zero+hist+scan into ONE
// single-block kernel (1024 thr, LDS hist of 3142 buckets + block scan).
// Scatter stays grid-wide (single-CU scattered stores would cost ~28us).
// Dispatches 5 -> 3. Gather unchanged.

#define VOCAB 50257
#define DIM   1024
#define NBUCK ((VOCAB + 15) >> 4)     // 3142 line-groups
#define NXCD  8
#define TPB   64                      // tokens per block
#define JSL   128                     // j-slice per block
#define NJS   (DIM / JSL)             // 8 j-slices
#define TSTR  65                      // LDS tile stride (floats)

// ---------- fused zero+hist+scan: one block, 1024 threads ----------
__global__ __launch_bounds__(1024) void sort_prep_kernel(
    const int* __restrict__ x, int n, int* __restrict__ offs)
{
    __shared__ int counts[NBUCK];            // 12568 B
    __shared__ int wtot[16];
    __shared__ int wbase[16];

    const int tid = threadIdx.x;

    // zero
    for (int i = tid; i < NBUCK; i += 1024) counts[i] = 0;
    __syncthreads();

    // hist: coalesced reads, LDS atomics
    for (int i = tid; i < n; i += 1024)
        atomicAdd(&counts[((unsigned)x[i]) >> 4], 1);
    __syncthreads();

    // block scan: thread t owns buckets 4t..4t+3
    int c[4];
    const int b0 = tid * 4;
#pragma unroll
    for (int k = 0; k < 4; ++k)
        c[k] = (b0 + k < NBUCK) ? counts[b0 + k] : 0;
    const int partial = c[0] + c[1] + c[2] + c[3];

    const int wave = tid >> 6, lane = tid & 63;
    int s = partial;                          // inclusive wave scan
    for (int d = 1; d < 64; d <<= 1) {
        int y = __shfl_up(s, d);
        if (lane >= d) s += y;
    }
    if (lane == 63) wtot[wave] = s;
    __syncthreads();
    if (tid < 16) {                           // exclusive scan of 16 wave totals
        int v = wtot[tid];
        int e = 0;
        for (int w = 0; w < 16; ++w) { if (w == tid) break; e += wtot[w]; }
        (void)v;
        wbase[tid] = e;
    }
    __syncthreads();

    int excl = wbase[wave] + s - partial;     // exclusive prefix of bucket b0
#pragma unroll
    for (int k = 0; k < 4; ++k) {
        if (b0 + k < NBUCK) offs[b0 + k] = excl;
        excl += c[k];
    }
}

// Packs (v << 16) | t. Intra-bucket order nondeterministic but out[t]
// depends only on t's own v -> deterministic OUTPUT.
__global__ void scatter_kernel(const int* __restrict__ x, int n,
                               int* __restrict__ offs, int* __restrict__ order) {
    int i = blockIdx.x * blockDim.x + threadIdx.x;
    if (i < n) {
        int v = x[i];
        int pos = atomicAdd(&offs[v >> 4], 1);
        order[pos] = (v << 16) | i;
    }
}

// ---------- gather: lanes = sorted tokens, j uniform; pipelined ----------
__global__ __launch_bounds__(256) void lane_sorted_gather(
    const float* __restrict__ W,
    const float* __restrict__ bias,
    const int* __restrict__ order,
    float* __restrict__ out,
    int n, int q, int r)   // q = nblk/8, r = nblk%8 (bijective XCD chunking)
{
    extern __shared__ float lds[];
    float* tile = lds;                       // [64][TSTR]
    int* tTok = (int*)(lds + TPB * TSTR);    // [64]

    const int bid = blockIdx.x;
    const int xcd = bid & (NXCD - 1);
    const int idx = bid >> 3;
    const int chunk_base = (xcd < r) ? xcd * (q + 1) : r * (q + 1) + (xcd - r) * q;
    const int L = chunk_base + idx;          // logical: consecutive L on one XCD
    const int g  = L >> 3;                   // token group (groups contiguous/XCD)
    const int js = L & 7;                    // j-slice 0..7

    const int tid = threadIdx.x;
    const int wave = tid >> 6;
    const int lane = tid & 63;

    const int t0 = g * TPB;
    const int cnt = min(TPB, n - t0);

    const unsigned pk = (unsigned)order[t0 + (lane < cnt ? lane : 0)]; // coalesced
    const int vl = (int)(pk >> 16);          // this lane's token's v (sorted)
    if (wave == 0) tTok[lane] = (int)(pk & 0xFFFFu);

    const int jb0 = js * JSL;
    const float* __restrict__ Wv = W + vl;   // per-lane column base
    const int jw = jb0 + wave * 16;          // this wave's 16 js, chunk 0
    const int tok = tid >> 2;                // store phase: token 0..63
    const int qq = tid & 3;                  // quad within 64-float chunk

    // ---- chunk 0 loads (16/lane), ~13 segments/instr (sorted lanes) ----
    float a0[8], b0[8];
#pragma unroll
    for (int i = 0; i < 8; ++i) a0[i] = Wv[(size_t)(jw + i) * VOCAB];
#pragma unroll
    for (int i = 0; i < 8; ++i) b0[i] = Wv[(size_t)(jw + 8 + i) * VOCAB];
    __builtin_amdgcn_sched_barrier(0);
#pragma unroll
    for (int i = 0; i < 8; ++i) tile[lane * TSTR + wave * 16 + i] = a0[i];
#pragma unroll
    for (int i = 0; i < 8; ++i) tile[lane * TSTR + wave * 16 + 8 + i] = b0[i];

    // ---- chunk 1 loads issued NOW: latency hides under chunk-0 stores ----
    float a1[8], b1[8];
#pragma unroll
    for (int i = 0; i < 8; ++i) a1[i] = Wv[(size_t)(jw + 64 + i) * VOCAB];
#pragma unroll
    for (int i = 0; i < 8; ++i) b1[i] = Wv[(size_t)(jw + 72 + i) * VOCAB];
    __builtin_amdgcn_sched_barrier(0);

    __syncthreads();                         // tile(ch0) + tTok ready

    // ---- stores chunk 0: 4 threads/token, 64B contiguous per instr ----
    const int t_out = (tok < cnt) ? tTok[tok] : -1;
    if (t_out >= 0) {
        float* __restrict__ dst = out + (size_t)t_out * DIM + jb0;
#pragma unroll
        for (int k = 0; k < 4; ++k) {
            const int jloc = k * 16 + qq * 4;
            float4 w4 = *reinterpret_cast<const float4*>(&tile[tok * TSTR + jloc]);
            const float4 b4 = *reinterpret_cast<const float4*>(&bias[jb0 + jloc]);
            w4.x += b4.x; w4.y += b4.y; w4.z += b4.z; w4.w += b4.w;
            *reinterpret_cast<float4*>(dst + jloc) = w4;
        }
    }
    __syncthreads();                         // ch0 stores done reading tile

    // ---- write chunk 1 into tile (waitcnt on a1/b1 auto-inserted) ----
#pragma unroll
    for (int i = 0; i < 8; ++i) tile[lane * TSTR + wave * 16 + i] = a1[i];
#pragma unroll
    for (int i = 0; i < 8; ++i) tile[lane * TSTR + wave * 16 + 8 + i] = b1[i];
    __syncthreads();                         // tile(ch1) ready

    // ---- stores chunk 1 ----
    if (t_out >= 0) {
        float* __restrict__ dst = out + (size_t)t_out * DIM + jb0 + 64;
#pragma unroll
        for (int k = 0; k < 4; ++k) {
            const int jloc = k * 16 + qq * 4;
            float4 w4 = *reinterpret_cast<const float4*>(&tile[tok * TSTR + jloc]);
            const float4 b4 = *reinterpret_cast<const float4*>(&bias[jb0 + 64 + jloc]);
            w4.x += b4.x; w4.y += b4.y; w4.z += b4.z; w4.w += b4.w;
            *reinterpret_cast<float4*>(dst + jloc) = w4;
        }
    }
}

// fallback (round-1 kernel) if workspace too small / n too large for packing
__global__ __launch_bounds__(256) void gather_direct_kernel(
    const int* __restrict__ x,
    const float* __restrict__ W,
    const float* __restrict__ bias,
    float* __restrict__ out)
{
    const int t = blockIdx.x;
    const int v = x[t];
    const int j0 = threadIdx.x * 4;
    float4 rr;
    rr.x = W[(size_t)(j0 + 0) * VOCAB + v];
    rr.y = W[(size_t)(j0 + 1) * VOCAB + v];
    rr.z = W[(size_t)(j0 + 2) * VOCAB + v];
    rr.w = W[(size_t)(j0 + 3) * VOCAB + v];
    const float4 bb = *reinterpret_cast<const float4*>(bias + j0);
    rr.x += bb.x; rr.y += bb.y; rr.z += bb.z; rr.w += bb.w;
    *reinterpret_cast<float4*>(out + (size_t)t * DIM + j0) = rr;
}

extern "C" void kernel_launch(void* const* d_in, const int* in_sizes, int n_in,
                              void* d_out, int out_size, void* d_ws, size_t ws_size,
                              hipStream_t stream) {
    const int*   x    = (const int*)d_in[0];
    const float* W    = (const float*)d_in[1];
    const float* bias = (const float*)d_in[2];
    float*       out  = (float*)d_out;

    const int n = in_sizes[0];           // 16384 tokens

    const size_t need = (size_t)(NBUCK + n) * sizeof(int);
    if (ws_size < need || n > 65536) {   // packing uses 16 bits for token id
        gather_direct_kernel<<<n, 256, 0, stream>>>(x, W, bias, out);
        return;
    }

    int* offs   = (int*)d_ws;            // [NBUCK] cursors
    int* order  = offs + NBUCK;          // [n] packed (v<<16 | t)

    sort_prep_kernel<<<1, 1024, 0, stream>>>(x, n, offs);
    const int tb = 256;
    scatter_kernel<<<(n + tb - 1) / tb, tb, 0, stream>>>(x, n, offs, order);

    const int ngroups = (n + TPB - 1) / TPB;     // 256
    const int nblk = ngroups * NJS;              // 2048
    const int q = nblk / NXCD, r = nblk % NXCD;
    const size_t lds_bytes = (TPB * TSTR) * sizeof(float) + TPB * sizeof(int);
    lane_sorted_gather<<<nblk, 256, lds_bytes, stream>>>(W, bias, order, out, n, q, r);
}

// Round 16
// 56.138 us; speedup vs baseline: 1.1704x; 1.0689x over previous
//
#include <hip/hip_runtime.h>

// out[t, j] = W[j, x[t]] + b[j]
//   x : [16384] int32, W : [1024, 50257] f32 row-major, b : [1024] f32
//   out: [16384, 1024] f32
//
// R12 (64.8us WIN): lanes = 64 SORTED tokens, j wave-uniform -> wave
// coalescer merges same-line lanes; ~3.2M W transactions = compulsory.
// R14 (60.0us): fused zero+hist+scan into one dispatch (5 -> 3).
// R15/16: final harvest. (1) gather in R12 loop form (16 live floats,
// max residency). (2) non-temporal out stores via native ext_vector
// (out is write-once; keep L2 for W slabs). (3) int4 hist reads.

#define VOCAB 50257
#define DIM   1024
#define NBUCK ((VOCAB + 15) >> 4)     // 3142 line-groups
#define NXCD  8
#define TPB   64                      // tokens per block
#define JSL   128                     // j-slice per block
#define NJS   (DIM / JSL)             // 8 j-slices
#define TSTR  65                      // LDS tile stride (floats)

typedef float f32x4 __attribute__((ext_vector_type(4)));  // NT-store-compatible

// ---------- fused zero+hist+scan: one block, 1024 threads ----------
__global__ __launch_bounds__(1024) void sort_prep_kernel(
    const int* __restrict__ x, int n, int* __restrict__ offs)
{
    __shared__ int counts[NBUCK];            // 12568 B
    __shared__ int wtot[16];
    __shared__ int wbase[16];

    const int tid = threadIdx.x;

    // zero
    for (int i = tid; i < NBUCK; i += 1024) counts[i] = 0;
    __syncthreads();

    // hist: int4-vectorized coalesced reads, LDS atomics
    const int n4 = n >> 2;
    const int4* __restrict__ x4 = (const int4*)x;
    for (int i = tid; i < n4; i += 1024) {
        const int4 v = x4[i];
        atomicAdd(&counts[((unsigned)v.x) >> 4], 1);
        atomicAdd(&counts[((unsigned)v.y) >> 4], 1);
        atomicAdd(&counts[((unsigned)v.z) >> 4], 1);
        atomicAdd(&counts[((unsigned)v.w) >> 4], 1);
    }
    for (int i = (n4 << 2) + tid; i < n; i += 1024)
        atomicAdd(&counts[((unsigned)x[i]) >> 4], 1);
    __syncthreads();

    // block scan: thread t owns buckets 4t..4t+3
    int c[4];
    const int b0 = tid * 4;
#pragma unroll
    for (int k = 0; k < 4; ++k)
        c[k] = (b0 + k < NBUCK) ? counts[b0 + k] : 0;
    const int partial = c[0] + c[1] + c[2] + c[3];

    const int wave = tid >> 6, lane = tid & 63;
    int s = partial;                          // inclusive wave scan
    for (int d = 1; d < 64; d <<= 1) {
        int y = __shfl_up(s, d);
        if (lane >= d) s += y;
    }
    if (lane == 63) wtot[wave] = s;
    __syncthreads();
    if (tid < 16) {                           // exclusive scan of 16 wave totals
        int e = 0;
        for (int w = 0; w < tid; ++w) e += wtot[w];
        wbase[tid] = e;
    }
    __syncthreads();

    int excl = wbase[wave] + s - partial;     // exclusive prefix of bucket b0
#pragma unroll
    for (int k = 0; k < 4; ++k) {
        if (b0 + k < NBUCK) offs[b0 + k] = excl;
        excl += c[k];
    }
}

// Packs (v << 16) | t. Intra-bucket order nondeterministic but out[t]
// depends only on t's own v -> deterministic OUTPUT.
__global__ void scatter_kernel(const int* __restrict__ x, int n,
                               int* __restrict__ offs, int* __restrict__ order) {
    int i = blockIdx.x * blockDim.x + threadIdx.x;
    if (i < n) {
        int v = x[i];
        int pos = atomicAdd(&offs[v >> 4], 1);
        order[pos] = (v << 16) | i;
    }
}

// ---------- gather: lanes = sorted tokens, j uniform per instr ----------
__global__ __launch_bounds__(256) void lane_sorted_gather(
    const float* __restrict__ W,
    const float* __restrict__ bias,
    const int* __restrict__ order,
    float* __restrict__ out,
    int n, int q, int r)   // q = nblk/8, r = nblk%8 (bijective XCD chunking)
{
    extern __shared__ float lds[];
    float* tile = lds;                       // [64][TSTR]
    int* tTok = (int*)(lds + TPB * TSTR);    // [64]

    const int bid = blockIdx.x;
    const int xcd = bid & (NXCD - 1);
    const int idx = bid >> 3;
    const int chunk_base = (xcd < r) ? xcd * (q + 1) : r * (q + 1) + (xcd - r) * q;
    const int L = chunk_base + idx;          // logical: consecutive L on one XCD
    const int g  = L >> 3;                   // token group (groups contiguous/XCD)
    const int js = L & 7;                    // j-slice 0..7

    const int tid = threadIdx.x;
    const int wave = tid >> 6;
    const int lane = tid & 63;

    const int t0 = g * TPB;
    const int cnt = min(TPB, n - t0);

    const unsigned pk = (unsigned)order[t0 + (lane < cnt ? lane : 0)]; // coalesced
    const int vl = (int)(pk >> 16);          // this lane's token's v (sorted)
    if (wave == 0) tTok[lane] = (int)(pk & 0xFFFFu);

    const int jb0 = js * JSL;
    const float* __restrict__ Wv = W + vl;   // per-lane column base
    const int tok = tid >> 2;                // store phase: token 0..63
    const int qq = tid & 3;                  // quad within 64-float chunk

#pragma unroll
    for (int ch = 0; ch < JSL / 64; ++ch) {  // 2 chunks of 64 j
        const int jb = jb0 + ch * 64 + wave * 16;  // this wave's 16 js

        // ---- load 8, fence, ds_write 8 (x2): ~13 segments/instr ----
        float a[8];
#pragma unroll
        for (int i = 0; i < 8; ++i)
            a[i] = Wv[(size_t)(jb + i) * VOCAB];
        __builtin_amdgcn_sched_barrier(0);
#pragma unroll
        for (int i = 0; i < 8; ++i)
            tile[lane * TSTR + wave * 16 + i] = a[i];

        float b[8];
#pragma unroll
        for (int i = 0; i < 8; ++i)
            b[i] = Wv[(size_t)(jb + 8 + i) * VOCAB];
        __builtin_amdgcn_sched_barrier(0);
#pragma unroll
        for (int i = 0; i < 8; ++i)
            tile[lane * TSTR + wave * 16 + 8 + i] = b[i];

        __syncthreads();                     // tile (and tTok on ch=0) ready

        // ---- store: 4 threads/token, 64B contiguous per instr, NT ----
        if (tok < cnt) {
            const int t = tTok[tok];
            float* __restrict__ dst = out + (size_t)t * DIM + jb0 + ch * 64;
#pragma unroll
            for (int k = 0; k < 4; ++k) {
                const int jloc = k * 16 + qq * 4;
                const float4 w4 = *reinterpret_cast<const float4*>(&tile[tok * TSTR + jloc]);
                const float4 b4 = *reinterpret_cast<const float4*>(&bias[jb0 + ch * 64 + jloc]);
                f32x4 o;
                o.x = w4.x + b4.x; o.y = w4.y + b4.y;
                o.z = w4.z + b4.z; o.w = w4.w + b4.w;
                __builtin_nontemporal_store(o, reinterpret_cast<f32x4*>(dst + jloc));
            }
        }
        __syncthreads();                     // before next chunk overwrites tile
    }
}

// fallback (round-1 kernel) if workspace too small / n too large for packing
__global__ __launch_bounds__(256) void gather_direct_kernel(
    const int* __restrict__ x,
    const float* __restrict__ W,
    const float* __restrict__ bias,
    float* __restrict__ out)
{
    const int t = blockIdx.x;
    const int v = x[t];
    const int j0 = threadIdx.x * 4;
    float4 rr;
    rr.x = W[(size_t)(j0 + 0) * VOCAB + v];
    rr.y = W[(size_t)(j0 + 1) * VOCAB + v];
    rr.z = W[(size_t)(j0 + 2) * VOCAB + v];
    rr.w = W[(size_t)(j0 + 3) * VOCAB + v];
    const float4 bb = *reinterpret_cast<const float4*>(bias + j0);
    rr.x += bb.x; rr.y += bb.y; rr.z += bb.z; rr.w += bb.w;
    *reinterpret_cast<float4*>(out + (size_t)t * DIM + j0) = rr;
}

extern "C" void kernel_launch(void* const* d_in, const int* in_sizes, int n_in,
                              void* d_out, int out_size, void* d_ws, size_t ws_size,
                              hipStream_t stream) {
    const int*   x    = (const int*)d_in[0];
    const float* W    = (const float*)d_in[1];
    const float* bias = (const float*)d_in[2];
    float*       out  = (float*)d_out;

    const int n = in_sizes[0];           // 16384 tokens

    const size_t need = (size_t)(NBUCK + n) * sizeof(int);
    if (ws_size < need || n > 65536) {   // packing uses 16 bits for token id
        gather_direct_kernel<<<n, 256, 0, stream>>>(x, W, bias, out);
        return;
    }

    int* offs   = (int*)d_ws;            // [NBUCK] cursors
    int* order  = offs + NBUCK;          // [n] packed (v<<16 | t)

    sort_prep_kernel<<<1, 1024, 0, stream>>>(x, n, offs);
    const int tb = 256;
    scatter_kernel<<<(n + tb - 1) / tb, tb, 0, stream>>>(x, n, offs, order);

    const int ngroups = (n + TPB - 1) / TPB;     // 256
    const int nblk = ngroups * NJS;              // 2048
    const int q = nblk / NXCD, r = nblk % NXCD;
    const size_t lds_bytes = (TPB * TSTR) * sizeof(float) + TPB * sizeof(int);
    lane_sorted_gather<<<nblk, 256, lds_bytes, stream>>>(W, bias, order, out, n, q, r);
}

// Round 17
// 54.106 us; speedup vs baseline: 1.2144x; 1.0376x over previous
//
#include <hip/hip_runtime.h>

// out[t, j] = W[j, x[t]] + b[j]
//   x : [16384] int32, W : [1024, 50257] f32 row-major, b : [1024] f32
//   out: [16384, 1024] f32
//
// R12 (64.8us WIN): lanes = 64 SORTED tokens, j wave-uniform -> wave
// coalescer merges same-line lanes; ~3.2M W transactions = compulsory.
// R14 (60.0us): fused zero+hist+scan into one dispatch (5 -> 3).
// R16 (56.1us): NT out stores + R12 loop form + int4 hist.
// R17: halve per-block overhead. 512-thread gather blocks (8 waves),
// JSL=256 (NJS 8->4, nblk 1024): half the barriers per j, half the
// order re-reads, half the block ramps. LDS [64][129]=33.3KB -> 4
// blocks/CU x 8 waves = 32 waves/CU (max, unchanged). Store: 8
// threads/token, each instr 128B contiguous per token.

#define VOCAB 50257
#define DIM   1024
#define NBUCK ((VOCAB + 15) >> 4)     // 3142 line-groups
#define NXCD  8
#define TPB   64                      // tokens per block
#define JSL   256                     // j-slice per block
#define NJS   (DIM / JSL)             // 4 j-slices
#define TSTR  129                     // LDS tile stride (floats)

typedef float f32x4 __attribute__((ext_vector_type(4)));  // NT-store-compatible

// ---------- fused zero+hist+scan: one block, 1024 threads ----------
__global__ __launch_bounds__(1024) void sort_prep_kernel(
    const int* __restrict__ x, int n, int* __restrict__ offs)
{
    __shared__ int counts[NBUCK];            // 12568 B
    __shared__ int wtot[16];
    __shared__ int wbase[16];

    const int tid = threadIdx.x;

    // zero
    for (int i = tid; i < NBUCK; i += 1024) counts[i] = 0;
    __syncthreads();

    // hist: int4-vectorized coalesced reads, LDS atomics
    const int n4 = n >> 2;
    const int4* __restrict__ x4 = (const int4*)x;
    for (int i = tid; i < n4; i += 1024) {
        const int4 v = x4[i];
        atomicAdd(&counts[((unsigned)v.x) >> 4], 1);
        atomicAdd(&counts[((unsigned)v.y) >> 4], 1);
        atomicAdd(&counts[((unsigned)v.z) >> 4], 1);
        atomicAdd(&counts[((unsigned)v.w) >> 4], 1);
    }
    for (int i = (n4 << 2) + tid; i < n; i += 1024)
        atomicAdd(&counts[((unsigned)x[i]) >> 4], 1);
    __syncthreads();

    // block scan: thread t owns buckets 4t..4t+3
    int c[4];
    const int b0 = tid * 4;
#pragma unroll
    for (int k = 0; k < 4; ++k)
        c[k] = (b0 + k < NBUCK) ? counts[b0 + k] : 0;
    const int partial = c[0] + c[1] + c[2] + c[3];

    const int wave = tid >> 6, lane = tid & 63;
    int s = partial;                          // inclusive wave scan
    for (int d = 1; d < 64; d <<= 1) {
        int y = __shfl_up(s, d);
        if (lane >= d) s += y;
    }
    if (lane == 63) wtot[wave] = s;
    __syncthreads();
    if (tid < 16) {                           // exclusive scan of 16 wave totals
        int e = 0;
        for (int w = 0; w < tid; ++w) e += wtot[w];
        wbase[tid] = e;
    }
    __syncthreads();

    int excl = wbase[wave] + s - partial;     // exclusive prefix of bucket b0
#pragma unroll
    for (int k = 0; k < 4; ++k) {
        if (b0 + k < NBUCK) offs[b0 + k] = excl;
        excl += c[k];
    }
}

// Packs (v << 16) | t. Intra-bucket order nondeterministic but out[t]
// depends only on t's own v -> deterministic OUTPUT.
__global__ void scatter_kernel(const int* __restrict__ x, int n,
                               int* __restrict__ offs, int* __restrict__ order) {
    int i = blockIdx.x * blockDim.x + threadIdx.x;
    if (i < n) {
        int v = x[i];
        int pos = atomicAdd(&offs[v >> 4], 1);
        order[pos] = (v << 16) | i;
    }
}

// ---------- gather: 512 thr, lanes = sorted tokens, j uniform ----------
__global__ __launch_bounds__(512) void lane_sorted_gather(
    const float* __restrict__ W,
    const float* __restrict__ bias,
    const int* __restrict__ order,
    float* __restrict__ out,
    int n, int q, int r)   // q = nblk/8, r = nblk%8 (bijective XCD chunking)
{
    extern __shared__ float lds[];
    float* tile = lds;                       // [64][TSTR]
    int* tTok = (int*)(lds + TPB * TSTR);    // [64]

    const int bid = blockIdx.x;
    const int xcd = bid & (NXCD - 1);
    const int idx = bid >> 3;
    const int chunk_base = (xcd < r) ? xcd * (q + 1) : r * (q + 1) + (xcd - r) * q;
    const int L = chunk_base + idx;          // logical: consecutive L on one XCD
    const int g  = L >> 2;                   // token group (groups contiguous/XCD)
    const int js = L & 3;                    // j-slice 0..3

    const int tid = threadIdx.x;
    const int wave = tid >> 6;               // 0..7
    const int lane = tid & 63;

    const int t0 = g * TPB;
    const int cnt = min(TPB, n - t0);

    const unsigned pk = (unsigned)order[t0 + (lane < cnt ? lane : 0)]; // coalesced
    const int vl = (int)(pk >> 16);          // this lane's token's v (sorted)
    if (wave == 0) tTok[lane] = (int)(pk & 0xFFFFu);

    const int jb0 = js * JSL;
    const float* __restrict__ Wv = W + vl;   // per-lane column base
    const int tok = tid >> 3;                // store phase: token 0..63
    const int sub = tid & 7;                 // 8 threads per token

#pragma unroll
    for (int ch = 0; ch < JSL / 128; ++ch) { // 2 chunks of 128 j
        const int jb = jb0 + ch * 128 + wave * 16;  // this wave's 16 js

        // ---- load 8, fence, ds_write 8 (x2): ~13 segments/instr ----
        float a[8];
#pragma unroll
        for (int i = 0; i < 8; ++i)
            a[i] = Wv[(size_t)(jb + i) * VOCAB];
        __builtin_amdgcn_sched_barrier(0);
#pragma unroll
        for (int i = 0; i < 8; ++i)
            tile[lane * TSTR + wave * 16 + i] = a[i];

        float b[8];
#pragma unroll
        for (int i = 0; i < 8; ++i)
            b[i] = Wv[(size_t)(jb + 8 + i) * VOCAB];
        __builtin_amdgcn_sched_barrier(0);
#pragma unroll
        for (int i = 0; i < 8; ++i)
            tile[lane * TSTR + wave * 16 + 8 + i] = b[i];

        __syncthreads();                     // tile (and tTok on ch=0) ready

        // ---- store: 8 threads/token, 128B contiguous per instr, NT ----
        if (tok < cnt) {
            const int t = tTok[tok];
            float* __restrict__ dst = out + (size_t)t * DIM + jb0 + ch * 128;
#pragma unroll
            for (int k = 0; k < 4; ++k) {
                const int jloc = k * 32 + sub * 4;
                const float4 w4 = *reinterpret_cast<const float4*>(&tile[tok * TSTR + jloc]);
                const float4 b4 = *reinterpret_cast<const float4*>(&bias[jb0 + ch * 128 + jloc]);
                f32x4 o;
                o.x = w4.x + b4.x; o.y = w4.y + b4.y;
                o.z = w4.z + b4.z; o.w = w4.w + b4.w;
                __builtin_nontemporal_store(o, reinterpret_cast<f32x4*>(dst + jloc));
            }
        }
        __syncthreads();                     // before next chunk overwrites tile
    }
}

// fallback (round-1 kernel) if workspace too small / n too large for packing
__global__ __launch_bounds__(256) void gather_direct_kernel(
    const int* __restrict__ x,
    const float* __restrict__ W,
    const float* __restrict__ bias,
    float* __restrict__ out)
{
    const int t = blockIdx.x;
    const int v = x[t];
    const int j0 = threadIdx.x * 4;
    float4 rr;
    rr.x = W[(size_t)(j0 + 0) * VOCAB + v];
    rr.y = W[(size_t)(j0 + 1) * VOCAB + v];
    rr.z = W[(size_t)(j0 + 2) * VOCAB + v];
    rr.w = W[(size_t)(j0 + 3) * VOCAB + v];
    const float4 bb = *reinterpret_cast<const float4*>(bias + j0);
    rr.x += bb.x; rr.y += bb.y; rr.z += bb.z; rr.w += bb.w;
    *reinterpret_cast<float4*>(out + (size_t)t * DIM + j0) = rr;
}

extern "C" void kernel_launch(void* const* d_in, const int* in_sizes, int n_in,
                              void* d_out, int out_size, void* d_ws, size_t ws_size,
                              hipStream_t stream) {
    const int*   x    = (const int*)d_in[0];
    const float* W    = (const float*)d_in[1];
    const float* bias = (const float*)d_in[2];
    float*       out  = (float*)d_out;

    const int n = in_sizes[0];           // 16384 tokens

    const size_t need = (size_t)(NBUCK + n) * sizeof(int);
    if (ws_size < need || n > 65536) {   // packing uses 16 bits for token id
        gather_direct_kernel<<<n, 256, 0, stream>>>(x, W, bias, out);
        return;
    }

    int* offs   = (int*)d_ws;            // [NBUCK] cursors
    int* order  = offs + NBUCK;          // [n] packed (v<<16 | t)

    sort_prep_kernel<<<1, 1024, 0, stream>>>(x, n, offs);
    const int tb = 256;
    scatter_kernel<<<(n + tb - 1) / tb, tb, 0, stream>>>(x, n, offs, order);

    const int ngroups = (n + TPB - 1) / TPB;     // 256
    const int nblk = ngroups * NJS;              // 1024
    const int q = nblk / NXCD, r = nblk % NXCD;
    const size_t lds_bytes = (TPB * TSTR) * sizeof(float) + TPB * sizeof(int);  // 33280
    lane_sorted_gather<<<nblk, 512, lds_bytes, stream>>>(W, bias, order, out, n, q, r);
}